// Round 1
// baseline (2331.396 us; speedup 1.0000x reference)
//
#include <hip/hip_runtime.h>
#include <math.h>

typedef __attribute__((ext_vector_type(8))) short short8;
typedef __attribute__((ext_vector_type(4))) float floatx4;

__device__ __forceinline__ unsigned short f2b(float f) {
  unsigned u = __builtin_bit_cast(unsigned, f);
  u += 0x7fffu + ((u >> 16) & 1u);
  return (unsigned short)(u >> 16);
}
__device__ __forceinline__ float b2f(unsigned short h) {
  unsigned u = ((unsigned)h) << 16;
  return __builtin_bit_cast(float, u);
}

// async global->LDS, 16B per lane. LDS dest = wave-uniform base + lane*16.
__device__ __forceinline__ void gload16(const void* g, void* l) {
  __builtin_amdgcn_global_load_lds(
      (const __attribute__((address_space(1))) void*)g,
      (__attribute__((address_space(3))) void*)l, 16, 0, 0);
}

// row remap: m -> (m/div)*mul + off + m%div  (div >= 2^30 == identity)
__device__ __forceinline__ long long rmap(int m, int div, int mul, int off) {
  if (m < div) return (long long)off + m;
  const unsigned q = (unsigned)m / (unsigned)div;
  return (long long)q * mul + off + (m - (int)q * div);
}

struct GemmP {
  int M, N, K, ldb;
  int adiv, amul, aoff;
  int cdiv, cmul, coff;
  long long boffE, coffE;
};

// ---------------------------------------------------------------------------
// Core: C[M,N] (op)= A[M,K] @ B^T   (A: bf16 [m][k], B: bf16 [n][k], both k-contig)
// 128x128 tile, BK=32, 4 waves (2x2), 4x4 frags/wave, global_load_lds staging.
// LDS layout [128 rows][4 chunks of 16B]; chunk position = c ^ ((row>>1)&3)
// (swizzle applied on the GLOBAL source per rule #21; ds_read uses same XOR).
// CMODE: 0 = store bf16, 1 = store f32, 2 = f32 +=
// Requires K%32==0; M,N may be ragged (staging clamps, epilogue guards).
// ---------------------------------------------------------------------------
template<int CMODE>
__device__ __forceinline__ void gemm_core(
    const unsigned short* __restrict__ A, int lda, int adiv, int amul, int aoff,
    const unsigned short* __restrict__ B, int ldb,
    void* __restrict__ Cp, long long coffE, int ldc, int cdiv, int cmul, int coff,
    int M, int N, int K, int m0, int n0,
    unsigned short* As, unsigned short* Bs)
{
  const int tid  = threadIdx.x;
  const int wave = tid >> 6, lane = tid & 63;
  const int lm = lane & 15, lq = lane >> 4;
  const int wr = wave >> 1, wc = wave & 1;

  // staging sources: chunk index i = wave*128 + j*64 + lane, j in {0,1}
  const unsigned short *aSrc0, *aSrc1, *bSrc0, *bSrc1;
  {
    const int i0 = wave * 128 + lane;
    {
      const int r = i0 >> 2;
      const int c = (i0 & 3) ^ ((r >> 1) & 3);
      int m = m0 + r; if (m >= M) m = M - 1;
      aSrc0 = A + rmap(m, adiv, amul, aoff) * lda + c * 8;
      int n = n0 + r; if (n >= N) n = N - 1;
      bSrc0 = B + (long long)n * ldb + c * 8;
    }
    const int i1 = i0 + 64;
    {
      const int r = i1 >> 2;
      const int c = (i1 & 3) ^ ((r >> 1) & 3);
      int m = m0 + r; if (m >= M) m = M - 1;
      aSrc1 = A + rmap(m, adiv, amul, aoff) * lda + c * 8;
      int n = n0 + r; if (n >= N) n = N - 1;
      bSrc1 = B + (long long)n * ldb + c * 8;
    }
  }
  unsigned short* aD0 = As + wave * 1024;
  unsigned short* aD1 = As + wave * 1024 + 512;
  unsigned short* bD0 = Bs + wave * 1024;
  unsigned short* bD1 = Bs + wave * 1024 + 512;

  floatx4 acc[4][4] = {};
  const int sw = (lm >> 1) & 3;   // == ((row>>1)&3) for all fragment rows

  for (int k0 = 0; k0 < K; k0 += 32) {
    gload16(aSrc0 + k0, aD0);
    gload16(aSrc1 + k0, aD1);
    gload16(bSrc0 + k0, bD0);
    gload16(bSrc1 + k0, bD1);
    __syncthreads();                     // implies vmcnt(0): staging landed

    short8 af[4], bf[4];
#pragma unroll
    for (int t = 0; t < 4; ++t) {
      const int ar = wr * 64 + t * 16 + lm;
      af[t] = *(const short8*)(As + ar * 32 + ((lq ^ sw) << 3));
      const int br = wc * 64 + t * 16 + lm;
      bf[t] = *(const short8*)(Bs + br * 32 + ((lq ^ sw) << 3));
    }
#pragma unroll
    for (int mi = 0; mi < 4; ++mi)
#pragma unroll
      for (int ni = 0; ni < 4; ++ni)
        acc[mi][ni] = __builtin_amdgcn_mfma_f32_16x16x32_bf16(af[mi], bf[ni], acc[mi][ni], 0, 0, 0);
    __syncthreads();
  }

#pragma unroll
  for (int mi = 0; mi < 4; ++mi) {
#pragma unroll
    for (int rr = 0; rr < 4; ++rr) {
      const int mg = m0 + wr * 64 + mi * 16 + lq * 4 + rr;
      if (mg >= M) continue;
      const long long crow = rmap(mg, cdiv, cmul, coff);
      const long long cb = coffE + crow * ldc + n0 + wc * 64 + lm;
#pragma unroll
      for (int ni = 0; ni < 4; ++ni) {
        const int ng = n0 + wc * 64 + ni * 16 + lm;
        if (ng >= N) continue;
        const float v = acc[mi][ni][rr];
        const long long idx = cb + ni * 16;
        if (CMODE == 0)      ((unsigned short*)Cp)[idx] = f2b(v);
        else if (CMODE == 1) ((float*)Cp)[idx] = v;
        else                 ((float*)Cp)[idx] += v;
      }
    }
  }
}

// fused dual-problem GEMM: blockIdx.z selects param set (prefix / expert).
template<int CMODE>
__global__ __launch_bounds__(256) void gemmF_k(
    const unsigned short* __restrict__ A, int lda,
    const unsigned short* __restrict__ B,
    void* __restrict__ Cp, int ldc,
    GemmP p0, GemmP p1)
{
  __shared__ alignas(16) unsigned short As[4096];
  __shared__ alignas(16) unsigned short Bs[4096];
  const GemmP p = blockIdx.z ? p1 : p0;
  const int m0 = blockIdx.y * 128, n0 = blockIdx.x * 128;
  if (m0 >= p.M || n0 >= p.N) return;
  gemm_core<CMODE>(A, lda, p.adiv, p.amul, p.aoff, B + p.boffE, p.ldb,
                   Cp, p.coffE, ldc, p.cdiv, p.cmul, p.coff,
                   p.M, p.N, p.K, m0, n0, As, Bs);
}

// batched GEMM (attention): z -> (zq,zr) operand offsets.
template<int CMODE>
__global__ __launch_bounds__(256) void gemmB_k(
    const unsigned short* __restrict__ A, int lda,
    const unsigned short* __restrict__ B, int ldb,
    void* __restrict__ Cp, int ldc,
    int M, int N, int K, int zdiv,
    long long aZ1, long long aZ2, long long bZ1, long long bZ2,
    long long cZ1, long long cZ2)
{
  __shared__ alignas(16) unsigned short As[4096];
  __shared__ alignas(16) unsigned short Bs[4096];
  const int z = blockIdx.z, zq = z / zdiv, zr = z % zdiv;
  const int BIG = 1 << 30;
  gemm_core<CMODE>(A + zq * aZ1 + zr * aZ2, lda, BIG, 0, 0,
                   B + zq * bZ1 + zr * bZ2, ldb,
                   Cp, zq * cZ1 + zr * cZ2, ldc, BIG, 0, 0,
                   M, N, K, blockIdx.y * 128, blockIdx.x * 128, As, Bs);
}

// ---------------------------------------------------------------------------
// weight transpose+convert: W fp32 [K][N] -> Wt bf16 [N][K].  grid (N/32, K/32)
// ---------------------------------------------------------------------------
__global__ __launch_bounds__(256) void wtrans_k(
    const float* __restrict__ W, unsigned short* __restrict__ Wt, int N, int K)
{
  __shared__ float tile[32][33];
  const int n0 = blockIdx.x << 5, k0 = blockIdx.y << 5;
  const int tid = threadIdx.x;
  const int r = tid >> 3, c4 = (tid & 7) << 2;
  const float4 v = *(const float4*)(W + (long long)(k0 + r) * N + n0 + c4);
  tile[r][c4] = v.x; tile[r][c4 + 1] = v.y; tile[r][c4 + 2] = v.z; tile[r][c4 + 3] = v.w;
  __syncthreads();
  ushort4 o;
  o.x = f2b(tile[c4 + 0][r]); o.y = f2b(tile[c4 + 1][r]);
  o.z = f2b(tile[c4 + 2][r]); o.w = f2b(tile[c4 + 3][r]);
  *(ushort4*)(Wt + (long long)(n0 + r) * K + k0 + c4) = o;
}

// concat prefix/suffix (fp32) into X, rows b*818 + t
__global__ __launch_bounds__(256) void concat_k(
    const float* __restrict__ pre, const float* __restrict__ suf, float* __restrict__ X)
{
  const long long i = (long long)blockIdx.x * 256 + threadIdx.x;  // float4 idx
  const int c  = (int)(i & 511);
  const int rr = (int)(i >> 9);
  const int bb = rr / 818, t = rr % 818;
  const float4* src = (t < 768)
      ? ((const float4*)pre + ((long long)bb * 768 + t) * 512 + c)
      : ((const float4*)suf + ((long long)bb * 50 + (t - 768)) * 512 + c);
  ((float4*)X)[i] = *src;
}

// RMSNorm: X fp32 (3272,2048) -> bf16 Nb, weight (1+w), w picked per stream
__global__ __launch_bounds__(256) void rmsnorm_k(
    const float* __restrict__ X, const float* __restrict__ wpre,
    const float* __restrict__ wsuf, unsigned short* __restrict__ out)
{
  const int r = blockIdx.x;
  const int t = r % 818;
  const float* w = (t < 768) ? wpre : wsuf;
  const float* x = X + (long long)r * 2048;
  const int tid = threadIdx.x;

  const float4 v0 = *(const float4*)(x + tid * 4);
  const float4 v1 = *(const float4*)(x + 1024 + tid * 4);
  float ss = v0.x*v0.x + v0.y*v0.y + v0.z*v0.z + v0.w*v0.w
           + v1.x*v1.x + v1.y*v1.y + v1.z*v1.z + v1.w*v1.w;
  for (int o = 32; o > 0; o >>= 1) ss += __shfl_down(ss, o);
  __shared__ float red[4];
  if ((tid & 63) == 0) red[tid >> 6] = ss;
  __syncthreads();
  const float mean = (red[0] + red[1] + red[2] + red[3]) * (1.0f / 2048.0f);
  const float rs = rsqrtf(mean + 1e-6f);

  const float4 w0 = *(const float4*)(w + tid * 4);
  const float4 w1 = *(const float4*)(w + 1024 + tid * 4);
  ushort4 o0, o1;
  o0.x = f2b(v0.x * rs * (1.0f + w0.x));
  o0.y = f2b(v0.y * rs * (1.0f + w0.y));
  o0.z = f2b(v0.z * rs * (1.0f + w0.z));
  o0.w = f2b(v0.w * rs * (1.0f + w0.w));
  o1.x = f2b(v1.x * rs * (1.0f + w1.x));
  o1.y = f2b(v1.y * rs * (1.0f + w1.y));
  o1.z = f2b(v1.z * rs * (1.0f + w1.z));
  o1.w = f2b(v1.w * rs * (1.0f + w1.w));
  *(ushort4*)(out + (long long)r * 2048 + tid * 4) = o0;
  *(ushort4*)(out + (long long)r * 2048 + 1024 + tid * 4) = o1;
}

// RoPE in place on QKVb rows (b*818+t, 2560): Q heads cols 0..2047, K cols 2048..2303
__global__ __launch_bounds__(256) void rope_k(
    unsigned short* __restrict__ QKV, const int* __restrict__ pos_ids)
{
  const int r = blockIdx.x;
  const int tid = threadIdx.x;
  __shared__ float cs[128], sn[128];
  if (tid < 128) {
    const float inv = expf(-(float)tid * (9.210340371976184f / 128.0f));
    const float f = (float)pos_ids[r] * inv;
    cs[tid] = cosf(f);
    sn[tid] = sinf(f);
  }
  __syncthreads();
  unsigned short* row = QKV + (long long)r * 2560;
  for (int w = tid; w < 9 * 128; w += 256) {
    const int h = w >> 7, d = w & 127;
    unsigned short* base = row + h * 256;     // h==8 lands exactly on K (col 2048)
    const float a = b2f(base[d]), bb = b2f(base[d + 128]);
    base[d]       = f2b(a * cs[d] - bb * sn[d]);
    base[d + 128] = f2b(bb * cs[d] + a * sn[d]);
  }
}

// V extract+transpose: QKVb cols 2304..2559 -> Vt (b,256,832), t>=818 zero
__global__ __launch_bounds__(256) void vtrans_k(
    const unsigned short* __restrict__ QKV, unsigned short* __restrict__ Vt)
{
  __shared__ unsigned short tile[32][36];
  const int b = blockIdx.z;
  const int t0 = blockIdx.x << 5, d0 = blockIdx.y << 5;
  const int tid = threadIdx.x;
  const int r = tid >> 3, c4 = (tid & 7) << 2;
  const int tt = t0 + r;
  ushort4 v = {0, 0, 0, 0};
  if (tt < 818)
    v = *(const ushort4*)(QKV + ((long long)(b * 818 + tt)) * 2560 + 2304 + d0 + c4);
  tile[r][c4] = v.x; tile[r][c4 + 1] = v.y; tile[r][c4 + 2] = v.z; tile[r][c4 + 3] = v.w;
  __syncthreads();
  ushort4 o;
  o.x = tile[c4 + 0][r]; o.y = tile[c4 + 1][r];
  o.z = tile[c4 + 2][r]; o.w = tile[c4 + 3][r];
  *(ushort4*)(Vt + ((long long)b * 256 + d0 + r) * 832 + t0 + c4) = o;
}

// masked softmax: S fp32 (B,H,818,832) -> P bf16 (pads zeroed)
__global__ __launch_bounds__(256) void softmax_k(
    const float* __restrict__ S, unsigned short* __restrict__ P)
{
  const long long r = blockIdx.x;
  const int q = (int)(r % 818);
  const float* s = S + r * 832;
  unsigned short* p = P + r * 832;
  const int tid = threadIdx.x;

  float vals[4];
  float mx = -3.0e38f;
#pragma unroll
  for (int i = 0; i < 4; ++i) {
    const int k = tid + i * 256;
    float v = -3.0e38f;
    if (k < 818 && ((k < 768) || (k <= q))) v = s[k] * 0.0625f;
    vals[i] = v;
    mx = fmaxf(mx, v);
  }
  for (int o = 32; o > 0; o >>= 1) mx = fmaxf(mx, __shfl_down(mx, o));
  __shared__ float red[4];
  if ((tid & 63) == 0) red[tid >> 6] = mx;
  __syncthreads();
  mx = fmaxf(fmaxf(red[0], red[1]), fmaxf(red[2], red[3]));
  __syncthreads();

  float sum = 0.f;
#pragma unroll
  for (int i = 0; i < 4; ++i) {
    const float e = __expf(vals[i] - mx);
    vals[i] = e;
    sum += e;
  }
  for (int o = 32; o > 0; o >>= 1) sum += __shfl_down(sum, o);
  if ((tid & 63) == 0) red[tid >> 6] = sum;
  __syncthreads();
  const float inv = 1.0f / (red[0] + red[1] + red[2] + red[3]);

#pragma unroll
  for (int i = 0; i < 4; ++i) {
    const int k = tid + i * 256;
    if (k < 832) p[k] = (k < 818) ? f2b(vals[i] * inv) : (unsigned short)0;
  }
}

// gate = gelu_tanh(gate) * up on interleaved GU rows [gate 8192 | up 8192]
__global__ __launch_bounds__(256) void gelumul_k(unsigned short* __restrict__ GU)
{
  const int i = blockIdx.x * 256 + threadIdx.x;   // < 3272*2048 (ushort4 units)
  const int r = i >> 11, c = (i & 2047) << 2;
  unsigned short* g = GU + (long long)r * 16384 + c;
  const ushort4 g4 = *(const ushort4*)g;
  const ushort4 u4 = *(const ushort4*)(g + 8192);
  ushort4 o;
  {
    const float x = b2f(g4.x), u = b2f(u4.x);
    o.x = f2b(0.5f * x * (1.0f + tanhf(0.7978845608f * (x + 0.044715f * x * x * x))) * u);
  }
  {
    const float x = b2f(g4.y), u = b2f(u4.y);
    o.y = f2b(0.5f * x * (1.0f + tanhf(0.7978845608f * (x + 0.044715f * x * x * x))) * u);
  }
  {
    const float x = b2f(g4.z), u = b2f(u4.z);
    o.z = f2b(0.5f * x * (1.0f + tanhf(0.7978845608f * (x + 0.044715f * x * x * x))) * u);
  }
  {
    const float x = b2f(g4.w), u = b2f(u4.w);
    o.w = f2b(0.5f * x * (1.0f + tanhf(0.7978845608f * (x + 0.044715f * x * x * x))) * u);
  }
  *(ushort4*)g = o;
}

// ---------------------------------------------------------------------------
extern "C" void kernel_launch(void* const* d_in, const int* in_sizes, int n_in,
                              void* d_out, int out_size, void* d_ws, size_t ws_size,
                              hipStream_t stream)
{
  const float* prefix  = (const float*)d_in[0];
  const float* suffix  = (const float*)d_in[1];
  const int*   pos_ids = (const int*)d_in[3];
  const float* p_ln1 = (const float*)d_in[4];
  const float* p_q   = (const float*)d_in[5];
  const float* p_k   = (const float*)d_in[6];
  const float* p_v   = (const float*)d_in[7];
  const float* p_o   = (const float*)d_in[8];
  const float* p_ln2 = (const float*)d_in[9];
  const float* p_g   = (const float*)d_in[10];
  const float* p_u   = (const float*)d_in[11];
  const float* p_d   = (const float*)d_in[12];
  const float* e_ln1 = (const float*)d_in[13];
  const float* e_q   = (const float*)d_in[14];
  const float* e_k   = (const float*)d_in[15];
  const float* e_v   = (const float*)d_in[16];
  const float* e_o   = (const float*)d_in[17];
  const float* e_ln2 = (const float*)d_in[18];
  const float* e_g   = (const float*)d_in[19];
  const float* e_u   = (const float*)d_in[20];
  const float* e_d   = (const float*)d_in[21];

  const int BIG = 1 << 30;
  float* X = (float*)d_out;               // residual (3272,2048) fp32 == output

  // ---- workspace layout (172,630,016 B total; phase-overlapped) ----
  char* ws = (char*)d_ws;
  unsigned short* const WSH = (unsigned short*)d_ws;     // element base for boffE
  const size_t QKV_OFF = 13402112;        // after Nb (3272*2048*2)
  const size_t VT_OFF  = 30154752;        // after QKVb (3272*2560*2)
  const size_t R_OFF   = 31858688;        // after Vt (4*256*832*2); R = 140,771,328 B

  unsigned short* Nb   = (unsigned short*)(ws);
  unsigned short* QKVb = (unsigned short*)(ws + QKV_OFF);  // also Att, also MLP e-weight slot
  unsigned short* Vt   = (unsigned short*)(ws + VT_OFF);
  float*          Sb   = (float*)(ws + R_OFF);
  unsigned short* Pb   = (unsigned short*)(ws + R_OFF + 87113728);
  unsigned short* GU   = (unsigned short*)(ws + R_OFF);                 // (3272,16384)
  unsigned short* qkvT_p = (unsigned short*)(ws + R_OFF);
  unsigned short* qkvT_e = (unsigned short*)(ws + R_OFF + 10485760);
  unsigned short* oT_p   = (unsigned short*)(ws + R_OFF);
  unsigned short* oT_e   = (unsigned short*)(ws + R_OFF + 8388608);
  unsigned short* wT_p   = (unsigned short*)(ws + R_OFF + 107216896);   // MLP p-weight slot
  unsigned short* wT_e   = (unsigned short*)(ws + QKV_OFF);             // MLP e-weight slot (Att dead)

  const long long QKVT_P_E = (long long)R_OFF / 2;
  const long long QKVT_E_E = (long long)(R_OFF + 10485760) / 2;
  const long long OT_P_E   = (long long)R_OFF / 2;
  const long long OT_E_E   = (long long)(R_OFF + 8388608) / 2;
  const long long WTP_E    = (long long)(R_OFF + 107216896) / 2;
  const long long WTE_E    = (long long)QKV_OFF / 2;

  concat_k<<<6544, 256, 0, stream>>>(prefix, suffix, X);

  for (int l = 0; l < 2; ++l) {
    const size_t oQ  = (size_t)l * 2048 * 2048;
    const size_t oKV = (size_t)l * 2048 * 256;
    const size_t oG  = (size_t)l * 2048 * 8192;
    const size_t oGe = (size_t)l * 2048 * 4096;
    const size_t oD  = (size_t)l * 8192 * 2048;
    const size_t oDe = (size_t)l * 4096 * 2048;
    const size_t oL  = (size_t)l * 2048;

    // ---- rmsnorm 1 ----
    rmsnorm_k<<<3272, 256, 0, stream>>>(X, p_ln1 + oL, e_ln1 + oL, Nb);

    // ---- weight transpose: qkv (prefix & expert) into one [2560][2048] each ----
    wtrans_k<<<dim3(64, 64), 256, 0, stream>>>(p_q + oQ,  qkvT_p,           2048, 2048);
    wtrans_k<<<dim3(8, 64),  256, 0, stream>>>(p_k + oKV, qkvT_p + 4194304, 256,  2048);
    wtrans_k<<<dim3(8, 64),  256, 0, stream>>>(p_v + oKV, qkvT_p + 4718592, 256,  2048);
    wtrans_k<<<dim3(64, 64), 256, 0, stream>>>(e_q + oQ,  qkvT_e,           2048, 2048);
    wtrans_k<<<dim3(8, 64),  256, 0, stream>>>(e_k + oKV, qkvT_e + 4194304, 256,  2048);
    wtrans_k<<<dim3(8, 64),  256, 0, stream>>>(e_v + oKV, qkvT_e + 4718592, 256,  2048);

    // ---- fused QKV projection (z=0 prefix, z=1 expert) ----
    {
      GemmP p0 = {3072, 2560, 2048, 2048, 768, 818, 0,   768, 818, 0,   QKVT_P_E, 0};
      GemmP p1 = {200,  2560, 2048, 2048, 50,  818, 768, 50,  818, 768, QKVT_E_E, 0};
      gemmF_k<0><<<dim3(20, 24, 2), 256, 0, stream>>>(Nb, 2048, WSH, QKVb, 2560, p0, p1);
    }

    rope_k<<<3272, 256, 0, stream>>>(QKVb, pos_ids);
    vtrans_k<<<dim3(26, 8, 4), 256, 0, stream>>>(QKVb, Vt);

    // ---- scores = Q @ K^T per (b,h) ----
    gemmB_k<1><<<dim3(7, 7, 32), 256, 0, stream>>>(
        QKVb, 2560, QKVb + 2048, 2560, Sb, 832,
        818, 818, 256, 8,
        818LL * 2560, 256, 818LL * 2560, 0, 5444608LL, 680576LL);

    softmax_k<<<26176, 256, 0, stream>>>(Sb, Pb);

    // ---- att = P @ V^T per (b,h), into Att (= QKVb region, QKV now dead) ----
    gemmB_k<0><<<dim3(2, 7, 32), 256, 0, stream>>>(
        Pb, 832, Vt, 832, QKVb, 2048,
        818, 256, 832, 8,
        5444608LL, 680576LL, 256LL * 832, 0, 818LL * 2048, 256);

    // ---- O projection (accumulate into X) ----
    wtrans_k<<<dim3(64, 64), 256, 0, stream>>>(p_o + oQ, oT_p, 2048, 2048);
    wtrans_k<<<dim3(64, 64), 256, 0, stream>>>(e_o + oQ, oT_e, 2048, 2048);
    {
      GemmP p0 = {3072, 2048, 2048, 2048, 768, 818, 0,   768, 818, 0,   OT_P_E, 0};
      GemmP p1 = {200,  2048, 2048, 2048, 50,  818, 768, 50,  818, 768, OT_E_E, 0};
      gemmF_k<2><<<dim3(16, 24, 2), 256, 0, stream>>>(QKVb, 2048, WSH, X, 2048, p0, p1);
    }

    // ---- rmsnorm 2 ----
    rmsnorm_k<<<3272, 256, 0, stream>>>(X, p_ln2 + oL, e_ln2 + oL, Nb);

    // ---- MLP gate ----
    wtrans_k<<<dim3(256, 64), 256, 0, stream>>>(p_g + oG,  wT_p, 8192, 2048);
    wtrans_k<<<dim3(128, 64), 256, 0, stream>>>(e_g + oGe, wT_e, 4096, 2048);
    {
      GemmP p0 = {3072, 8192, 2048, 2048, 768, 818, 0,   BIG, 0, 0,    WTP_E, 0};
      GemmP p1 = {200,  4096, 2048, 2048, 50,  818, 768, BIG, 0, 3072, WTE_E, 0};
      gemmF_k<0><<<dim3(64, 24, 2), 256, 0, stream>>>(Nb, 2048, WSH, GU, 16384, p0, p1);
    }
    // ---- MLP up (into GU cols 8192+) ----
    wtrans_k<<<dim3(256, 64), 256, 0, stream>>>(p_u + oG,  wT_p, 8192, 2048);
    wtrans_k<<<dim3(128, 64), 256, 0, stream>>>(e_u + oGe, wT_e, 4096, 2048);
    {
      GemmP p0 = {3072, 8192, 2048, 2048, 768, 818, 0,   BIG, 0, 0,    WTP_E, 8192};
      GemmP p1 = {200,  4096, 2048, 2048, 50,  818, 768, BIG, 0, 3072, WTE_E, 8192};
      gemmF_k<0><<<dim3(64, 24, 2), 256, 0, stream>>>(Nb, 2048, WSH, GU, 16384, p0, p1);
    }

    gelumul_k<<<26176, 256, 0, stream>>>(GU);

    // ---- down projection (accumulate into X) ----
    wtrans_k<<<dim3(64, 256), 256, 0, stream>>>(p_d + oD,  wT_p, 2048, 8192);
    wtrans_k<<<dim3(64, 128), 256, 0, stream>>>(e_d + oDe, wT_e, 2048, 4096);
    {
      GemmP p0 = {3072, 2048, 8192, 8192, BIG, 0, 0,    768, 818, 0,   WTP_E, 0};
      GemmP p1 = {200,  2048, 4096, 4096, BIG, 0, 3072, 50,  818, 768, WTE_E, 0};
      gemmF_k<2><<<dim3(16, 24, 2), 256, 0, stream>>>(GU, 16384, WSH, X, 2048, p0, p1);
    }
  }
  (void)in_sizes; (void)n_in; (void)out_size; (void)ws_size;
}